// Round 6
// baseline (121.503 us; speedup 1.0000x reference)
//
#include <hip/hip_runtime.h>

// IntLayerNorm (quantized), D=1024. One wave per row, RPW=2 rows per wave:
// balances w/b amortization (R4) against TLP (R3: 64 waves/CU best).
// 8192 waves = 32/CU. Nontemporal x-loads / out-stores (streaming, no reuse).
// Memory-bound: 64MB read + 64MB write.

typedef float floatx4 __attribute__((ext_vector_type(4)));  // native vec for nt builtins

constexpr int Dn   = 1024;
constexpr int QD   = 16;   // Q_D
constexpr int INVD = 64;   // round(2^16 / 1024)
constexpr int QLUT = 15;
constexpr int RPW  = 2;    // rows per wave
// Q_W = 8 -> scale 256, output divide 1/256

__global__ __launch_bounds__(256) void intln_kernel(
    const float* __restrict__ x,
    const float* __restrict__ w,
    const float* __restrict__ b,
    const int* __restrict__ lut,         // 32 x int32
    float* __restrict__ out,
    int nrows)
{
    const int lane = threadIdx.x & 63;
    const int wid  = threadIdx.x >> 6;            // 0..3
    const int gw   = blockIdx.x * 4 + wid;        // global wave id
    const int row0 = gw * RPW;
    if (row0 >= nrows) return;
    const int coff = lane * 4;                    // within-chunk column offset

    // ---- quantize w/b once per wave (rows share them; L1/L2 hits) ----
    int wq[16], bq[16];
#pragma unroll
    for (int c = 0; c < 4; ++c) {
        const floatx4 wv = *reinterpret_cast<const floatx4*>(w + c * 256 + coff);
        const floatx4 bv = *reinterpret_cast<const floatx4*>(b + c * 256 + coff);
#pragma unroll
        for (int j = 0; j < 4; ++j) {
            wq[c*4+j] = __float2int_rn(wv[j] * 256.0f);
            bq[c*4+j] = __float2int_rn(bv[j] * 256.0f);
        }
    }

#pragma unroll
    for (int r = 0; r < RPW; ++r) {
        const size_t rbase = (size_t)(row0 + r) * Dn;

        // ---- load x: 4 coalesced nontemporal 16B chunks (1KB/wave/instr) ----
        floatx4 xv[4];
#pragma unroll
        for (int c = 0; c < 4; ++c)
            xv[c] = __builtin_nontemporal_load(
                        reinterpret_cast<const floatx4*>(x + rbase + c * 256 + coff));

        int xi[16];
#pragma unroll
        for (int c = 0; c < 4; ++c)
#pragma unroll
            for (int j = 0; j < 4; ++j)
                xi[c*4+j] = __float2int_rn(xv[c][j]);

        int s = 0, ss = 0;                        // per-lane partials fit int32
#pragma unroll
        for (int j = 0; j < 16; ++j) { s += xi[j]; ss += xi[j] * xi[j]; }

        // ---- wave butterfly reduce (int32) ----
#pragma unroll
        for (int off = 32; off; off >>= 1) {
            s  += __shfl_xor(s,  off, 64);
            ss += __shfl_xor(ss, off, 64);
        }

        // ---- uniform per-row tail: int64, bit-exact vs reference ----
        const long long S  = s;
        const long long SS = ss;
        const long long mean64 = (S * INVD) >> QD;
        const long long sum_sq = SS - 2 * mean64 * S + (long long)Dn * mean64 * mean64;
        long long var = (sum_sq * INVD) >> QD;
        if (var < 1) var = 1;

        const int k  = 63 - __clzll((unsigned long long)var);   // floor(log2(var))
        const int sa = k - 4;                                   // M = 4
        const int mant = (sa >= 0) ? (int)((var >> sa) & 15)
                                   : (int)((var << (-sa)) & 15);
        const int idx = ((k & 1) << 4) | mant;
        const int inv = lut[idx];                               // uniform addr
        const int tot = (k >> 1) + QLUT;                        // p + SHIFT(0) + Q_LUT
        const int mean = (int)mean64;

        // ---- per-element: y*inv (int32), one 32x32->64 widening mul, shift ----
        float ov[16];
#pragma unroll
        for (int j = 0; j < 16; ++j) {
            const int yi = xi[j] - mean;
            const int t  = yi * inv;                  // |yi|*2^15 < 2^31
            const long long prod = (long long)t * wq[j];
            ov[j] = (float)((int)(prod >> tot) + bq[j]) * 0.00390625f;
        }

#pragma unroll
        for (int c = 0; c < 4; ++c) {
            floatx4 o = { ov[c*4+0], ov[c*4+1], ov[c*4+2], ov[c*4+3] };
            __builtin_nontemporal_store(o,
                reinterpret_cast<floatx4*>(out + rbase + c * 256 + coff));
        }
    }
}

extern "C" void kernel_launch(void* const* d_in, const int* in_sizes, int n_in,
                              void* d_out, int out_size, void* d_ws, size_t ws_size,
                              hipStream_t stream) {
    const float* x   = (const float*)d_in[0];
    const float* w   = (const float*)d_in[1];
    const float* b   = (const float*)d_in[2];
    const int*   lut = (const int*)d_in[3];
    float* out = (float*)d_out;

    const int nrows  = in_sizes[0] / Dn;                   // 8*2048 = 16384
    const int blocks = (nrows + 4 * RPW - 1) / (4 * RPW);  // 4 waves/block
    intln_kernel<<<blocks, 256, 0, stream>>>(x, w, b, lut, out, nrows);
}

// Round 7
// 116.525 us; speedup vs baseline: 1.0427x; 1.0427x over previous
//
#include <hip/hip_runtime.h>

// IntLayerNorm (quantized), D=1024. ONE WAVE PER ROW (best measured: R3,
// 115.0us vs 118.1 RPW=4, 121.5 RPW=2+nt, 124.5 LDS-block): 64 lanes x 16
// elems, barrier-free shfl_xor reduce, 32-bit element math, int64 only for
// the uniform per-row tail. 16384 waves = 64/CU -> max TLP, which beat all
// instruction-count-reduction variants. Memory-bound: 64MB read + 64MB write.

constexpr int Dn   = 1024;
constexpr int QD   = 16;   // Q_D
constexpr int INVD = 64;   // round(2^16 / 1024)
constexpr int QLUT = 15;
// Q_W = 8 -> scale 256, output divide 1/256

__global__ __launch_bounds__(256) void intln_kernel(
    const float* __restrict__ x,
    const float* __restrict__ w,
    const float* __restrict__ b,
    const int* __restrict__ lut,         // 32 x int32
    float* __restrict__ out,
    int nrows)
{
    const int lane = threadIdx.x & 63;
    const int wid  = threadIdx.x >> 6;          // 0..3, each wave owns a row
    const int row  = blockIdx.x * 4 + wid;
    if (row >= nrows) return;

    const size_t rbase = (size_t)row * Dn;
    const int    coff  = lane * 4;              // within-chunk offset

    // ---- load x: 4 coalesced float4 chunks (lane*16B, 1KB/wave/instr) ----
    float4 xv0 = *reinterpret_cast<const float4*>(x + rbase + 0   + coff);
    float4 xv1 = *reinterpret_cast<const float4*>(x + rbase + 256 + coff);
    float4 xv2 = *reinterpret_cast<const float4*>(x + rbase + 512 + coff);
    float4 xv3 = *reinterpret_cast<const float4*>(x + rbase + 768 + coff);
    // w/b chunks (L1/L2-resident after first blocks) — issue early
    float4 wv0 = *reinterpret_cast<const float4*>(w + 0   + coff);
    float4 wv1 = *reinterpret_cast<const float4*>(w + 256 + coff);
    float4 wv2 = *reinterpret_cast<const float4*>(w + 512 + coff);
    float4 wv3 = *reinterpret_cast<const float4*>(w + 768 + coff);
    float4 bv0 = *reinterpret_cast<const float4*>(b + 0   + coff);
    float4 bv1 = *reinterpret_cast<const float4*>(b + 256 + coff);
    float4 bv2 = *reinterpret_cast<const float4*>(b + 512 + coff);
    float4 bv3 = *reinterpret_cast<const float4*>(b + 768 + coff);

    int xi[16];
    xi[0]=__float2int_rn(xv0.x); xi[1]=__float2int_rn(xv0.y); xi[2]=__float2int_rn(xv0.z); xi[3]=__float2int_rn(xv0.w);
    xi[4]=__float2int_rn(xv1.x); xi[5]=__float2int_rn(xv1.y); xi[6]=__float2int_rn(xv1.z); xi[7]=__float2int_rn(xv1.w);
    xi[8]=__float2int_rn(xv2.x); xi[9]=__float2int_rn(xv2.y); xi[10]=__float2int_rn(xv2.z); xi[11]=__float2int_rn(xv2.w);
    xi[12]=__float2int_rn(xv3.x); xi[13]=__float2int_rn(xv3.y); xi[14]=__float2int_rn(xv3.z); xi[15]=__float2int_rn(xv3.w);

    int s = 0, ss = 0;                          // per-lane partials fit int32
#pragma unroll
    for (int j = 0; j < 16; ++j) { s += xi[j]; ss += xi[j] * xi[j]; }

    // ---- wave butterfly reduce (all lanes end with full sums), int32 ----
#pragma unroll
    for (int off = 32; off; off >>= 1) {
        s  += __shfl_xor(s,  off, 64);
        ss += __shfl_xor(ss, off, 64);
    }

    // ---- uniform per-row tail: int64, bit-exact vs reference ----
    const long long S  = s;
    const long long SS = ss;
    const long long mean64 = (S * INVD) >> QD;                    // fixed-point mean
    const long long sum_sq = SS - 2 * mean64 * S + (long long)Dn * mean64 * mean64;
    long long var = (sum_sq * INVD) >> QD;
    if (var < 1) var = 1;

    const int k  = 63 - __clzll((unsigned long long)var);         // floor(log2(var))
    const int sa = k - 4;                                         // M = 4
    const int mant = (sa >= 0) ? (int)((var >> sa) & 15)
                               : (int)((var << (-sa)) & 15);
    const int idx = ((k & 1) << 4) | mant;
    const int inv = lut[idx];                                     // uniform addr
    const int tot = (k >> 1) + QLUT;                              // p + SHIFT(0) + Q_LUT
    const int mean = (int)mean64;

    // ---- per-element: 32-bit y*inv, one 32x32->64 widening mul, shift ----
    float ov[16];
#pragma unroll
    for (int j = 0; j < 16; ++j) {
        const float wf = (j<4 ? (&wv0.x)[j] : j<8 ? (&wv1.x)[j-4] : j<12 ? (&wv2.x)[j-8] : (&wv3.x)[j-12]);
        const float bf = (j<4 ? (&bv0.x)[j] : j<8 ? (&bv1.x)[j-4] : j<12 ? (&bv2.x)[j-8] : (&bv3.x)[j-12]);
        const int wq = __float2int_rn(wf * 256.0f);
        const int bq = __float2int_rn(bf * 256.0f);
        const int yi = xi[j] - mean;                  // |yi| small
        const int t  = yi * inv;                      // fits int32 (|yi|*2^15 < 2^31)
        const long long prod = (long long)t * wq;     // 32x32->64
        ov[j] = (float)((int)(prod >> tot) + bq) * 0.00390625f;
    }

    float4 o0 = { ov[0], ov[1], ov[2], ov[3] };
    float4 o1 = { ov[4], ov[5], ov[6], ov[7] };
    float4 o2 = { ov[8], ov[9], ov[10], ov[11] };
    float4 o3 = { ov[12], ov[13], ov[14], ov[15] };
    *reinterpret_cast<float4*>(out + rbase + 0   + coff) = o0;
    *reinterpret_cast<float4*>(out + rbase + 256 + coff) = o1;
    *reinterpret_cast<float4*>(out + rbase + 512 + coff) = o2;
    *reinterpret_cast<float4*>(out + rbase + 768 + coff) = o3;
}

extern "C" void kernel_launch(void* const* d_in, const int* in_sizes, int n_in,
                              void* d_out, int out_size, void* d_ws, size_t ws_size,
                              hipStream_t stream) {
    const float* x   = (const float*)d_in[0];
    const float* w   = (const float*)d_in[1];
    const float* b   = (const float*)d_in[2];
    const int*   lut = (const int*)d_in[3];
    float* out = (float*)d_out;

    const int nrows = in_sizes[0] / Dn;          // 8*2048 = 16384
    const int blocks = (nrows + 3) / 4;          // 4 rows (waves) per block
    intln_kernel<<<blocks, 256, 0, stream>>>(x, w, b, lut, out, nrows);
}